// Round 5
// baseline (177.377 us; speedup 1.0000x reference)
//
#include <hip/hip_runtime.h>
#include <cstdint>

#define SEQ 4096
#define NH 8
#define DH 32

typedef __bf16 bf16x8 __attribute__((ext_vector_type(8)));
typedef float f32x4 __attribute__((ext_vector_type(4)));
typedef float f32x8 __attribute__((ext_vector_type(8)));
typedef float f32x16 __attribute__((ext_vector_type(16)));
typedef unsigned short u16x8 __attribute__((ext_vector_type(8)));
typedef unsigned u32x4 __attribute__((ext_vector_type(4)));
typedef unsigned u32x2 __attribute__((ext_vector_type(2)));
typedef int i32x2 __attribute__((ext_vector_type(2)));

#define MFMA16 __builtin_amdgcn_mfma_f32_16x16x32_bf16
#define MFMA32 __builtin_amdgcn_mfma_f32_32x32x16_bf16

#define QSCALE 0.25503902427f /* (1/sqrt(32)) * log2(e) */

__device__ inline bf16x8 ld_bf8(const unsigned short* p) {
    return __builtin_bit_cast(bf16x8, *(const u16x8*)p);
}
__device__ inline unsigned short bfbits(float v) {
    return __builtin_bit_cast(unsigned short, (__bf16)v);
}
__device__ inline bf16x8 cvt_f8(f32x8 v) {
    bf16x8 r;
#pragma unroll
    for (int i = 0; i < 8; i++) r[i] = (__bf16)v[i];
    return r;
}
__device__ inline unsigned cvtpk(float lo, float hi) {
    unsigned r;
    asm("v_cvt_pk_bf16_f32 %0, %1, %2" : "=v"(r) : "v"(lo), "v"(hi));
    return r;
}

// ---------------- Kernel 0: preconvert f32 -> bf16 ----------------
__global__ __launch_bounds__(256) void precvt_kernel(
    const float* __restrict__ x0, const float* __restrict__ x1, const float* __restrict__ x2,
    const float* __restrict__ w0, const float* __restrict__ w1, const float* __restrict__ w2,
    const float* __restrict__ w3,
    unsigned short* __restrict__ bx0, unsigned short* __restrict__ bx1,
    unsigned short* __restrict__ bx2, unsigned short* __restrict__ bw0,
    unsigned short* __restrict__ bw1, unsigned short* __restrict__ bw2,
    unsigned short* __restrict__ bw3) {
    const int i = blockIdx.x * 256 + threadIdx.x;
    const float* src;
    unsigned short* dst;
    int off;
    float scale = 1.0f;
    if (i < 393216) {
        const int sel = i >> 17;
        off = i & 131071;
        src = (sel == 0) ? x0 : (sel == 1) ? x1 : x2;
        dst = (sel == 0) ? bx0 : (sel == 1) ? bx1 : bx2;
        if (sel == 0) scale = QSCALE;
    } else {
        const int j = i - 393216;
        const int sel = j >> 13;
        off = j & 8191;
        src = (sel == 0) ? w0 : (sel == 1) ? w1 : (sel == 2) ? w2 : w3;
        dst = (sel == 0) ? bw0 : (sel == 1) ? bw1 : (sel == 2) ? bw2 : bw3;
    }
    f32x8 v = ((const f32x8*)src)[off];
    u16x8 r;
#pragma unroll
    for (int j = 0; j < 8; j++) r[j] = bfbits(v[j] * scale);
    ((u16x8*)dst)[off] = r;
}

// ---------------- Kernel 1: QKV projections, bf16 inputs ----------------
__global__ __launch_bounds__(256, 4) void proj_bf16_kernel(
    const unsigned short* __restrict__ X0, const unsigned short* __restrict__ X1,
    const unsigned short* __restrict__ X2, const unsigned short* __restrict__ W0,
    const unsigned short* __restrict__ W1, const unsigned short* __restrict__ W2,
    const float* __restrict__ radial,
    unsigned short* __restrict__ outq, unsigned short* __restrict__ outk,
    unsigned short* __restrict__ outv) {
    const int sel = blockIdx.y;
    const unsigned short* X = (sel == 0) ? X0 : (sel == 1) ? X1 : X2;
    const unsigned short* W = (sel == 0) ? W0 : (sel == 1) ? W1 : W2;
    const int lane = threadIdx.x & 63;
    const int w = threadIdx.x >> 6;
    const int cl = lane & 15;
    const int h4 = lane >> 4;
    const int t = blockIdx.x * 4 + w;
    const int m0 = (t >> 3) * 32;
    const int n0 = (t & 7) * 32;

    const unsigned short* xa0 = X + (m0 + cl) * 256 + h4 * 8;
    const unsigned short* xa1 = xa0 + 16 * 256;
    const unsigned short* wb0 = W + (n0 + cl) * 256 + h4 * 8;
    const unsigned short* wb1 = wb0 + 16 * 256;

    f32x4 acc00 = {0.f, 0.f, 0.f, 0.f}, acc01 = {0.f, 0.f, 0.f, 0.f};
    f32x4 acc10 = {0.f, 0.f, 0.f, 0.f}, acc11 = {0.f, 0.f, 0.f, 0.f};
#pragma unroll
    for (int ksi = 0; ksi < 8; ksi++) {
        bf16x8 a0 = ld_bf8(xa0 + ksi * 32);
        bf16x8 a1 = ld_bf8(xa1 + ksi * 32);
        bf16x8 b0 = ld_bf8(wb0 + ksi * 32);
        bf16x8 b1 = ld_bf8(wb1 + ksi * 32);
        acc00 = MFMA16(a0, b0, acc00, 0, 0, 0);
        acc01 = MFMA16(a0, b1, acc01, 0, 0, 0);
        acc10 = MFMA16(a1, b0, acc10, 0, 0, 0);
        acc11 = MFMA16(a1, b1, acc11, 0, 0, 0);
    }

#pragma unroll
    for (int am = 0; am < 2; am++) {
#pragma unroll
        for (int r = 0; r < 4; r++) {
            const int cm = m0 + am * 16 + h4 * 4 + r;
            float rm = (sel == 2) ? radial[cm] : 0.f;
#pragma unroll
            for (int bn = 0; bn < 2; bn++) {
                float v = am ? (bn ? acc11[r] : acc10[r]) : (bn ? acc01[r] : acc00[r]);
                const int cn = n0 + bn * 16 + cl;
                const int h = cn >> 5, d = cn & 31;
                if (sel == 0) outq[(h * SEQ + cm) * DH + d] = bfbits(v);
                else if (sel == 1) outk[(h * SEQ + cm) * DH + d] = bfbits(v);
                else outv[(h * DH + d) * SEQ + cm] = bfbits(v * rm);
            }
        }
    }
}

// ---- fallback (small ws): proj with inline f32->bf16 conversion ----
__global__ __launch_bounds__(256) void proj_f32_kernel(
    const float* __restrict__ X0, const float* __restrict__ X1, const float* __restrict__ X2,
    const float* __restrict__ W0, const float* __restrict__ W1, const float* __restrict__ W2,
    const float* __restrict__ radial,
    unsigned short* __restrict__ outq, unsigned short* __restrict__ outk,
    unsigned short* __restrict__ outv) {
    const int sel = blockIdx.y;
    const float* X = (sel == 0) ? X0 : (sel == 1) ? X1 : X2;
    const float* W = (sel == 0) ? W0 : (sel == 1) ? W1 : W2;
    const int lane = threadIdx.x & 63;
    const int w = threadIdx.x >> 6;
    const int cl = lane & 15;
    const int h4 = lane >> 4;
    const int t = blockIdx.x * 4 + w;
    const int m0 = (t >> 3) * 32;
    const int n0 = (t & 7) * 32;

    const float* xa0 = X + (m0 + cl) * 256 + h4 * 8;
    const float* xa1 = xa0 + 16 * 256;
    const float* wb0 = W + (n0 + cl) * 256 + h4 * 8;
    const float* wb1 = wb0 + 16 * 256;

    f32x4 acc00 = {0.f, 0.f, 0.f, 0.f}, acc01 = {0.f, 0.f, 0.f, 0.f};
    f32x4 acc10 = {0.f, 0.f, 0.f, 0.f}, acc11 = {0.f, 0.f, 0.f, 0.f};
#pragma unroll
    for (int ksi = 0; ksi < 8; ksi++) {
        bf16x8 a0 = cvt_f8(*(const f32x8*)(xa0 + ksi * 32));
        bf16x8 a1 = cvt_f8(*(const f32x8*)(xa1 + ksi * 32));
        bf16x8 b0 = cvt_f8(*(const f32x8*)(wb0 + ksi * 32));
        bf16x8 b1 = cvt_f8(*(const f32x8*)(wb1 + ksi * 32));
        acc00 = MFMA16(a0, b0, acc00, 0, 0, 0);
        acc01 = MFMA16(a0, b1, acc01, 0, 0, 0);
        acc10 = MFMA16(a1, b0, acc10, 0, 0, 0);
        acc11 = MFMA16(a1, b1, acc11, 0, 0, 0);
    }
#pragma unroll
    for (int am = 0; am < 2; am++) {
#pragma unroll
        for (int r = 0; r < 4; r++) {
            const int cm = m0 + am * 16 + h4 * 4 + r;
            float rm = (sel == 2) ? radial[cm] : 0.f;
#pragma unroll
            for (int bn = 0; bn < 2; bn++) {
                float v = am ? (bn ? acc11[r] : acc10[r]) : (bn ? acc01[r] : acc00[r]);
                const int cn = n0 + bn * 16 + cl;
                const int h = cn >> 5, d = cn & 31;
                if (sel == 0) outq[(h * SEQ + cm) * DH + d] = bfbits(v * QSCALE);
                else if (sel == 1) outk[(h * SEQ + cm) * DH + d] = bfbits(v);
                else outv[(h * DH + d) * SEQ + cm] = bfbits(v * rm);
            }
        }
    }
}

// ---------------- Kernel 2: flash attention ----------------
// Block = 512 threads = 8 waves = one 32-row q-tile x 8 key-eighths (512 keys
// each, 16 iters). 1024 blocks -> 8192 waves = 8 waves/SIMD (100% occupancy)
// so dependency/L2-latency stalls interleave across waves.
// Swapped-operand MFMAs keep softmax lane-local; KSPLIT combine via LDS.
__device__ inline void attn_step(bf16x8 kf0, bf16x8 kf1, bf16x8 vt0, bf16x8 vt1,
                                 const bf16x8& qf0, const bf16x8& qf1,
                                 f32x16& oacc, float& ls) {
    f32x16 s = {0.f, 0.f, 0.f, 0.f, 0.f, 0.f, 0.f, 0.f,
                0.f, 0.f, 0.f, 0.f, 0.f, 0.f, 0.f, 0.f};
    __builtin_amdgcn_s_setprio(1);
    s = MFMA32(kf0, qf0, s, 0, 0, 0);
    s = MFMA32(kf1, qf1, s, 0, 0, 0);
    __builtin_amdgcn_s_setprio(0);
    float p[16];
#pragma unroll
    for (int r = 0; r < 16; r++) p[r] = __builtin_amdgcn_exp2f(s[r]);
    {
        float s01 = p[0] + p[1], s23 = p[2] + p[3], s45 = p[4] + p[5], s67 = p[6] + p[7];
        float s89 = p[8] + p[9], sab = p[10] + p[11], scd = p[12] + p[13], sef = p[14] + p[15];
        ls += ((s01 + s23) + (s45 + s67)) + ((s89 + sab) + (scd + sef));
    }
    unsigned a01 = cvtpk(p[0], p[1]), a23 = cvtpk(p[2], p[3]);
    unsigned a45 = cvtpk(p[4], p[5]), a67 = cvtpk(p[6], p[7]);
    i32x2 r0 = __builtin_amdgcn_permlane32_swap((int)a01, (int)a45, false, false);
    i32x2 r1 = __builtin_amdgcn_permlane32_swap((int)a23, (int)a67, false, false);
    u32x4 pb0w = {(unsigned)r0[0], (unsigned)r1[0], (unsigned)r0[1], (unsigned)r1[1]};
    unsigned a89 = cvtpk(p[8], p[9]), aab = cvtpk(p[10], p[11]);
    unsigned acd = cvtpk(p[12], p[13]), aef = cvtpk(p[14], p[15]);
    i32x2 r2 = __builtin_amdgcn_permlane32_swap((int)a89, (int)acd, false, false);
    i32x2 r3 = __builtin_amdgcn_permlane32_swap((int)aab, (int)aef, false, false);
    u32x4 pb1w = {(unsigned)r2[0], (unsigned)r3[0], (unsigned)r2[1], (unsigned)r3[1]};
    __builtin_amdgcn_s_setprio(1);
    oacc = MFMA32(vt0, __builtin_bit_cast(bf16x8, pb0w), oacc, 0, 0, 0);
    oacc = MFMA32(vt1, __builtin_bit_cast(bf16x8, pb1w), oacc, 0, 0, 0);
    __builtin_amdgcn_s_setprio(0);
}

__global__ __launch_bounds__(512, 8) void attn_kernel(
    const unsigned short* __restrict__ Q, const unsigned short* __restrict__ K,
    const unsigned short* __restrict__ Vt, unsigned short* __restrict__ An) {
    __shared__ float cO[7][64][17];
    __shared__ float cls[7][32];
    const int lane = threadIdx.x & 63;
    const int w = threadIdx.x >> 6;  // key-eighth, 0..7
    const int l31 = lane & 31;
    const int hi = lane >> 5;

    // XCD-chunked remap: 1024 blocks head-major -> each XCD owns one head
    int bid = blockIdx.x;
    bid = (bid & 7) * 128 + (bid >> 3);
    const int head = bid >> 7;
    const int m0 = (bid & 127) * 32;

    const unsigned short* qh = Q + head * (SEQ * DH);
    const unsigned short* kh = K + head * (SEQ * DH);
    const unsigned short* vh = Vt + head * (DH * SEQ);

    const bf16x8 qf0 = ld_bf8(qh + (m0 + l31) * DH + hi * 8);       // d in [0,16)
    const bf16x8 qf1 = ld_bf8(qh + (m0 + l31) * DH + 16 + hi * 8);  // d in [16,32)

    f32x16 oacc = {0.f, 0.f, 0.f, 0.f, 0.f, 0.f, 0.f, 0.f,
                   0.f, 0.f, 0.f, 0.f, 0.f, 0.f, 0.f, 0.f};
    float ls = 0.f;

    const unsigned short* kp = kh + (w * 512 + l31) * DH + hi * 8;
    const unsigned short* vp = vh + l31 * SEQ + w * 512 + hi * 8;

    bf16x8 kc0 = ld_bf8(kp), kc1 = ld_bf8(kp + 16);
    bf16x8 vc0 = ld_bf8(vp), vc1 = ld_bf8(vp + 16);
    for (int nb = 0; nb < 15; nb++) {
        kp += 32 * DH;
        vp += 32;
        bf16x8 kn0 = ld_bf8(kp), kn1 = ld_bf8(kp + 16);
        bf16x8 vn0 = ld_bf8(vp), vn1 = ld_bf8(vp + 16);
        attn_step(kc0, kc1, vc0, vc1, qf0, qf1, oacc, ls);
        kc0 = kn0; kc1 = kn1; vc0 = vn0; vc1 = vn1;
    }
    attn_step(kc0, kc1, vc0, vc1, qf0, qf1, oacc, ls);

    ls += __shfl_xor(ls, 32);
    if (w > 0) {
#pragma unroll
        for (int i = 0; i < 16; i++) cO[w - 1][lane][i] = oacc[i];
        if (hi == 0) cls[w - 1][l31] = ls;
    }
    __syncthreads();
    if (w == 0) {
#pragma unroll
        for (int j = 0; j < 7; j++) {
#pragma unroll
            for (int i = 0; i < 16; i++) oacc[i] += cO[j][lane][i];
            ls += cls[j][l31];
        }
        const float inv = 1.0f / ls;
        unsigned short* op = An + (m0 + l31) * 256 + head * DH;
#pragma unroll
        for (int g = 0; g < 4; g++) {
            unsigned lo = cvtpk(oacc[4 * g] * inv, oacc[4 * g + 1] * inv);
            unsigned hw = cvtpk(oacc[4 * g + 2] * inv, oacc[4 * g + 3] * inv);
            *(u32x2*)(op + 8 * g + 4 * hi) = (u32x2){lo, hw};
        }
    }
}

// ---------------- Kernel 3: output projection, bf16 Wo ----------------
__global__ __launch_bounds__(256, 4) void oproj_bf16_kernel(
    const unsigned short* __restrict__ An, const unsigned short* __restrict__ Wo,
    float* __restrict__ out) {
    const int lane = threadIdx.x & 63;
    const int w = threadIdx.x >> 6;
    const int cl = lane & 15;
    const int h4 = lane >> 4;
    const int t = blockIdx.x * 4 + w;
    const int m0 = (t >> 4) * 32;
    const int n0 = (t & 15) * 16;

    const unsigned short* ap0 = An + (m0 + cl) * 256 + h4 * 8;
    const unsigned short* ap1 = ap0 + 16 * 256;
    const unsigned short* wb0 = Wo + (n0 + cl) * 256 + h4 * 8;

    f32x4 acc00 = {0.f, 0.f, 0.f, 0.f}, acc10 = {0.f, 0.f, 0.f, 0.f};
#pragma unroll
    for (int ksi = 0; ksi < 8; ksi++) {
        bf16x8 a0 = ld_bf8(ap0 + ksi * 32);
        bf16x8 a1 = ld_bf8(ap1 + ksi * 32);
        bf16x8 b0 = ld_bf8(wb0 + ksi * 32);
        acc00 = MFMA16(a0, b0, acc00, 0, 0, 0);
        acc10 = MFMA16(a1, b0, acc10, 0, 0, 0);
    }
#pragma unroll
    for (int am = 0; am < 2; am++) {
#pragma unroll
        for (int r = 0; r < 4; r++) {
            const int cm = m0 + am * 16 + h4 * 4 + r;
            out[cm * 256 + n0 + cl] = am ? acc10[r] : acc00[r];
        }
    }
}

// ---- fallback oproj (f32 Wo, inline cvt) ----
__global__ __launch_bounds__(256) void oproj_f32_kernel(
    const unsigned short* __restrict__ An, const float* __restrict__ Wo,
    float* __restrict__ out) {
    const int lane = threadIdx.x & 63;
    const int w = threadIdx.x >> 6;
    const int cl = lane & 15;
    const int h4 = lane >> 4;
    const int t = blockIdx.x * 4 + w;
    const int m0 = (t >> 3) * 32;
    const int n0 = (t & 7) * 32;

    const unsigned short* ap0 = An + (m0 + cl) * 256 + h4 * 8;
    const unsigned short* ap1 = ap0 + 16 * 256;
    const float* wb0 = Wo + (n0 + cl) * 256 + h4 * 8;
    const float* wb1 = wb0 + 16 * 256;

    f32x4 acc00 = {0.f, 0.f, 0.f, 0.f}, acc01 = {0.f, 0.f, 0.f, 0.f};
    f32x4 acc10 = {0.f, 0.f, 0.f, 0.f}, acc11 = {0.f, 0.f, 0.f, 0.f};
#pragma unroll
    for (int ksi = 0; ksi < 8; ksi++) {
        bf16x8 a0 = ld_bf8(ap0 + ksi * 32);
        bf16x8 a1 = ld_bf8(ap1 + ksi * 32);
        bf16x8 b0 = cvt_f8(*(const f32x8*)(wb0 + ksi * 32));
        bf16x8 b1 = cvt_f8(*(const f32x8*)(wb1 + ksi * 32));
        acc00 = MFMA16(a0, b0, acc00, 0, 0, 0);
        acc01 = MFMA16(a0, b1, acc01, 0, 0, 0);
        acc10 = MFMA16(a1, b0, acc10, 0, 0, 0);
        acc11 = MFMA16(a1, b1, acc11, 0, 0, 0);
    }
#pragma unroll
    for (int am = 0; am < 2; am++) {
#pragma unroll
        for (int r = 0; r < 4; r++) {
            const int cm = m0 + am * 16 + h4 * 4 + r;
#pragma unroll
            for (int bn = 0; bn < 2; bn++) {
                float v = am ? (bn ? acc11[r] : acc10[r]) : (bn ? acc01[r] : acc00[r]);
                out[cm * 256 + n0 + bn * 16 + cl] = v;
            }
        }
    }
}

extern "C" void kernel_launch(void* const* d_in, const int* in_sizes, int n_in,
                              void* d_out, int out_size, void* d_ws, size_t ws_size,
                              hipStream_t stream) {
    const float* query = (const float*)d_in[0];
    const float* key_ = (const float*)d_in[1];
    const float* value = (const float*)d_in[2];
    const float* radial = (const float*)d_in[3];
    const float* Wq = (const float*)d_in[4];
    const float* Wk = (const float*)d_in[5];
    const float* Wv = (const float*)d_in[6];
    const float* Wo = (const float*)d_in[7];

    const size_t MB = 1u << 20;
    uint8_t* base = (uint8_t*)d_ws;
    unsigned short* wq = (unsigned short*)(base + 0 * MB);
    unsigned short* wk = (unsigned short*)(base + 2 * MB);
    unsigned short* wv = (unsigned short*)(base + 4 * MB);
    unsigned short* wa = (unsigned short*)(base + 6 * MB);

    const bool big = ws_size >= (size_t)(15.5 * 1024 * 1024);
    if (big) {
        unsigned short* bX0 = (unsigned short*)(base + 8 * MB);
        unsigned short* bX1 = (unsigned short*)(base + 10 * MB);
        unsigned short* bX2 = (unsigned short*)(base + 12 * MB);
        unsigned short* bWq = (unsigned short*)(base + 14 * MB);
        unsigned short* bWk = (unsigned short*)(base + 14 * MB + 128 * 1024);
        unsigned short* bWv = (unsigned short*)(base + 14 * MB + 256 * 1024);
        unsigned short* bWo = (unsigned short*)(base + 14 * MB + 384 * 1024);
        precvt_kernel<<<1664, 256, 0, stream>>>(query, key_, value, Wq, Wk, Wv, Wo,
                                                bX0, bX1, bX2, bWq, bWk, bWv, bWo);
        proj_bf16_kernel<<<dim3(256, 3), 256, 0, stream>>>(bX0, bX1, bX2, bWq, bWk, bWv,
                                                           radial, wq, wk, wv);
        attn_kernel<<<1024, 512, 0, stream>>>(wq, wk, wv, wa);
        oproj_bf16_kernel<<<512, 256, 0, stream>>>(wa, bWo, (float*)d_out);
    } else {
        proj_f32_kernel<<<dim3(256, 3), 256, 0, stream>>>(query, key_, value, Wq, Wk, Wv,
                                                          radial, wq, wk, wv);
        attn_kernel<<<1024, 512, 0, stream>>>(wq, wk, wv, wa);
        oproj_f32_kernel<<<256, 256, 0, stream>>>(wa, Wo, (float*)d_out);
    }
}

// Round 6
// 91.084 us; speedup vs baseline: 1.9474x; 1.9474x over previous
//
#include <hip/hip_runtime.h>
#include <cstdint>

#define SEQ 4096
#define NH 8
#define DH 32

typedef __bf16 bf16x8 __attribute__((ext_vector_type(8)));
typedef float f32x4 __attribute__((ext_vector_type(4)));
typedef float f32x8 __attribute__((ext_vector_type(8)));
typedef float f32x16 __attribute__((ext_vector_type(16)));
typedef unsigned short u16x8 __attribute__((ext_vector_type(8)));
typedef unsigned u32x4 __attribute__((ext_vector_type(4)));
typedef unsigned u32x2 __attribute__((ext_vector_type(2)));
typedef int i32x2 __attribute__((ext_vector_type(2)));

#define MFMA16 __builtin_amdgcn_mfma_f32_16x16x32_bf16
#define MFMA32 __builtin_amdgcn_mfma_f32_32x32x16_bf16

#define QSCALE 0.25503902427f /* (1/sqrt(32)) * log2(e) */

__device__ inline bf16x8 ld_bf8(const unsigned short* p) {
    return __builtin_bit_cast(bf16x8, *(const u16x8*)p);
}
__device__ inline unsigned short bfbits(float v) {
    return __builtin_bit_cast(unsigned short, (__bf16)v);
}
__device__ inline bf16x8 cvt_f8(f32x8 v) {
    bf16x8 r;
#pragma unroll
    for (int i = 0; i < 8; i++) r[i] = (__bf16)v[i];
    return r;
}
__device__ inline unsigned cvtpk(float lo, float hi) {
    unsigned r;
    asm("v_cvt_pk_bf16_f32 %0, %1, %2" : "=v"(r) : "v"(lo), "v"(hi));
    return r;
}

// ---------------- Kernel 0: preconvert f32 -> bf16 ----------------
__global__ __launch_bounds__(256) void precvt_kernel(
    const float* __restrict__ x0, const float* __restrict__ x1, const float* __restrict__ x2,
    const float* __restrict__ w0, const float* __restrict__ w1, const float* __restrict__ w2,
    const float* __restrict__ w3,
    unsigned short* __restrict__ bx0, unsigned short* __restrict__ bx1,
    unsigned short* __restrict__ bx2, unsigned short* __restrict__ bw0,
    unsigned short* __restrict__ bw1, unsigned short* __restrict__ bw2,
    unsigned short* __restrict__ bw3) {
    const int i = blockIdx.x * 256 + threadIdx.x;
    const float* src;
    unsigned short* dst;
    int off;
    float scale = 1.0f;
    if (i < 393216) {
        const int sel = i >> 17;
        off = i & 131071;
        src = (sel == 0) ? x0 : (sel == 1) ? x1 : x2;
        dst = (sel == 0) ? bx0 : (sel == 1) ? bx1 : bx2;
        if (sel == 0) scale = QSCALE;
    } else {
        const int j = i - 393216;
        const int sel = j >> 13;
        off = j & 8191;
        src = (sel == 0) ? w0 : (sel == 1) ? w1 : (sel == 2) ? w2 : w3;
        dst = (sel == 0) ? bw0 : (sel == 1) ? bw1 : (sel == 2) ? bw2 : bw3;
    }
    f32x8 v = ((const f32x8*)src)[off];
    u16x8 r;
#pragma unroll
    for (int j = 0; j < 8; j++) r[j] = bfbits(v[j] * scale);
    ((u16x8*)dst)[off] = r;
}

// ---------------- Kernel 1: QKV projections, bf16 inputs ----------------
__global__ __launch_bounds__(256, 4) void proj_bf16_kernel(
    const unsigned short* __restrict__ X0, const unsigned short* __restrict__ X1,
    const unsigned short* __restrict__ X2, const unsigned short* __restrict__ W0,
    const unsigned short* __restrict__ W1, const unsigned short* __restrict__ W2,
    const float* __restrict__ radial,
    unsigned short* __restrict__ outq, unsigned short* __restrict__ outk,
    unsigned short* __restrict__ outv) {
    const int sel = blockIdx.y;
    const unsigned short* X = (sel == 0) ? X0 : (sel == 1) ? X1 : X2;
    const unsigned short* W = (sel == 0) ? W0 : (sel == 1) ? W1 : W2;
    const int lane = threadIdx.x & 63;
    const int w = threadIdx.x >> 6;
    const int cl = lane & 15;
    const int h4 = lane >> 4;
    const int t = blockIdx.x * 4 + w;
    const int m0 = (t >> 3) * 32;
    const int n0 = (t & 7) * 32;

    const unsigned short* xa0 = X + (m0 + cl) * 256 + h4 * 8;
    const unsigned short* xa1 = xa0 + 16 * 256;
    const unsigned short* wb0 = W + (n0 + cl) * 256 + h4 * 8;
    const unsigned short* wb1 = wb0 + 16 * 256;

    f32x4 acc00 = {0.f, 0.f, 0.f, 0.f}, acc01 = {0.f, 0.f, 0.f, 0.f};
    f32x4 acc10 = {0.f, 0.f, 0.f, 0.f}, acc11 = {0.f, 0.f, 0.f, 0.f};
#pragma unroll
    for (int ksi = 0; ksi < 8; ksi++) {
        bf16x8 a0 = ld_bf8(xa0 + ksi * 32);
        bf16x8 a1 = ld_bf8(xa1 + ksi * 32);
        bf16x8 b0 = ld_bf8(wb0 + ksi * 32);
        bf16x8 b1 = ld_bf8(wb1 + ksi * 32);
        acc00 = MFMA16(a0, b0, acc00, 0, 0, 0);
        acc01 = MFMA16(a0, b1, acc01, 0, 0, 0);
        acc10 = MFMA16(a1, b0, acc10, 0, 0, 0);
        acc11 = MFMA16(a1, b1, acc11, 0, 0, 0);
    }

#pragma unroll
    for (int am = 0; am < 2; am++) {
#pragma unroll
        for (int r = 0; r < 4; r++) {
            const int cm = m0 + am * 16 + h4 * 4 + r;
            float rm = (sel == 2) ? radial[cm] : 0.f;
#pragma unroll
            for (int bn = 0; bn < 2; bn++) {
                float v = am ? (bn ? acc11[r] : acc10[r]) : (bn ? acc01[r] : acc00[r]);
                const int cn = n0 + bn * 16 + cl;
                const int h = cn >> 5, d = cn & 31;
                if (sel == 0) outq[(h * SEQ + cm) * DH + d] = bfbits(v);
                else if (sel == 1) outk[(h * SEQ + cm) * DH + d] = bfbits(v);
                else outv[(h * DH + d) * SEQ + cm] = bfbits(v * rm);
            }
        }
    }
}

// ---- fallback (small ws): proj with inline f32->bf16 conversion ----
__global__ __launch_bounds__(256) void proj_f32_kernel(
    const float* __restrict__ X0, const float* __restrict__ X1, const float* __restrict__ X2,
    const float* __restrict__ W0, const float* __restrict__ W1, const float* __restrict__ W2,
    const float* __restrict__ radial,
    unsigned short* __restrict__ outq, unsigned short* __restrict__ outk,
    unsigned short* __restrict__ outv) {
    const int sel = blockIdx.y;
    const float* X = (sel == 0) ? X0 : (sel == 1) ? X1 : X2;
    const float* W = (sel == 0) ? W0 : (sel == 1) ? W1 : W2;
    const int lane = threadIdx.x & 63;
    const int w = threadIdx.x >> 6;
    const int cl = lane & 15;
    const int h4 = lane >> 4;
    const int t = blockIdx.x * 4 + w;
    const int m0 = (t >> 3) * 32;
    const int n0 = (t & 7) * 32;

    const float* xa0 = X + (m0 + cl) * 256 + h4 * 8;
    const float* xa1 = xa0 + 16 * 256;
    const float* wb0 = W + (n0 + cl) * 256 + h4 * 8;
    const float* wb1 = wb0 + 16 * 256;

    f32x4 acc00 = {0.f, 0.f, 0.f, 0.f}, acc01 = {0.f, 0.f, 0.f, 0.f};
    f32x4 acc10 = {0.f, 0.f, 0.f, 0.f}, acc11 = {0.f, 0.f, 0.f, 0.f};
#pragma unroll
    for (int ksi = 0; ksi < 8; ksi++) {
        bf16x8 a0 = cvt_f8(*(const f32x8*)(xa0 + ksi * 32));
        bf16x8 a1 = cvt_f8(*(const f32x8*)(xa1 + ksi * 32));
        bf16x8 b0 = cvt_f8(*(const f32x8*)(wb0 + ksi * 32));
        bf16x8 b1 = cvt_f8(*(const f32x8*)(wb1 + ksi * 32));
        acc00 = MFMA16(a0, b0, acc00, 0, 0, 0);
        acc01 = MFMA16(a0, b1, acc01, 0, 0, 0);
        acc10 = MFMA16(a1, b0, acc10, 0, 0, 0);
        acc11 = MFMA16(a1, b1, acc11, 0, 0, 0);
    }
#pragma unroll
    for (int am = 0; am < 2; am++) {
#pragma unroll
        for (int r = 0; r < 4; r++) {
            const int cm = m0 + am * 16 + h4 * 4 + r;
            float rm = (sel == 2) ? radial[cm] : 0.f;
#pragma unroll
            for (int bn = 0; bn < 2; bn++) {
                float v = am ? (bn ? acc11[r] : acc10[r]) : (bn ? acc01[r] : acc00[r]);
                const int cn = n0 + bn * 16 + cl;
                const int h = cn >> 5, d = cn & 31;
                if (sel == 0) outq[(h * SEQ + cm) * DH + d] = bfbits(v * QSCALE);
                else if (sel == 1) outk[(h * SEQ + cm) * DH + d] = bfbits(v);
                else outv[(h * DH + d) * SEQ + cm] = bfbits(v * rm);
            }
        }
    }
}

// ---------------- shared attention inner step ----------------
__device__ inline void attn_step(bf16x8 kf0, bf16x8 kf1, bf16x8 vt0, bf16x8 vt1,
                                 const bf16x8& qf0, const bf16x8& qf1,
                                 f32x16& oacc, float& ls) {
    f32x16 s = {0.f, 0.f, 0.f, 0.f, 0.f, 0.f, 0.f, 0.f,
                0.f, 0.f, 0.f, 0.f, 0.f, 0.f, 0.f, 0.f};
    __builtin_amdgcn_s_setprio(1);
    s = MFMA32(kf0, qf0, s, 0, 0, 0);
    s = MFMA32(kf1, qf1, s, 0, 0, 0);
    __builtin_amdgcn_s_setprio(0);
    float p[16];
#pragma unroll
    for (int r = 0; r < 16; r++) p[r] = __builtin_amdgcn_exp2f(s[r]);
    {
        float s01 = p[0] + p[1], s23 = p[2] + p[3], s45 = p[4] + p[5], s67 = p[6] + p[7];
        float s89 = p[8] + p[9], sab = p[10] + p[11], scd = p[12] + p[13], sef = p[14] + p[15];
        ls += ((s01 + s23) + (s45 + s67)) + ((s89 + sab) + (scd + sef));
    }
    unsigned a01 = cvtpk(p[0], p[1]), a23 = cvtpk(p[2], p[3]);
    unsigned a45 = cvtpk(p[4], p[5]), a67 = cvtpk(p[6], p[7]);
    i32x2 r0 = __builtin_amdgcn_permlane32_swap((int)a01, (int)a45, false, false);
    i32x2 r1 = __builtin_amdgcn_permlane32_swap((int)a23, (int)a67, false, false);
    u32x4 pb0w = {(unsigned)r0[0], (unsigned)r1[0], (unsigned)r0[1], (unsigned)r1[1]};
    unsigned a89 = cvtpk(p[8], p[9]), aab = cvtpk(p[10], p[11]);
    unsigned acd = cvtpk(p[12], p[13]), aef = cvtpk(p[14], p[15]);
    i32x2 r2 = __builtin_amdgcn_permlane32_swap((int)a89, (int)acd, false, false);
    i32x2 r3 = __builtin_amdgcn_permlane32_swap((int)aab, (int)aef, false, false);
    u32x4 pb1w = {(unsigned)r2[0], (unsigned)r3[0], (unsigned)r2[1], (unsigned)r3[1]};
    __builtin_amdgcn_s_setprio(1);
    oacc = MFMA32(vt0, __builtin_bit_cast(bf16x8, pb0w), oacc, 0, 0, 0);
    oacc = MFMA32(vt1, __builtin_bit_cast(bf16x8, pb1w), oacc, 0, 0, 0);
    __builtin_amdgcn_s_setprio(0);
}

// ---------------- Kernel 2a: flash attention, block-shared K/V stream ----------------
// Block = 512 thr = 8 waves = 8 q-tiles (256 q-rows), all reading the SAME
// key-quarter chunk each iter (per-iter barrier keeps the window in L1, so
// each K/V line is fetched from L2 once per BLOCK, not once per wave —
// attacks the measured ~16 B/cyc/CU L1-fill cap). K-split is across blocks;
// f32 partials (O^T, ls) go to workspace, combined by combine_kernel.
__global__ __launch_bounds__(512, 4) void attn_shared_kernel(
    const unsigned short* __restrict__ Q, const unsigned short* __restrict__ K,
    const unsigned short* __restrict__ Vt, float* __restrict__ pO,
    float* __restrict__ pls) {
    const int lane = threadIdx.x & 63;
    const int w = threadIdx.x >> 6;  // q-tile within octet, 0..7
    const int l31 = lane & 31;
    const int hi = lane >> 5;

    // 512 blocks head-major: each XCD owns one head's K/V in its L2
    int bid = blockIdx.x;
    bid = (bid & 7) * 64 + (bid >> 3);
    const int head = bid >> 6;
    const int qoct = (bid >> 2) & 15;
    const int kq = bid & 3;
    const int qt128 = qoct * 8 + w;  // q-tile within head [0,128)
    const int m0 = qt128 * 32;

    const unsigned short* qh = Q + head * (SEQ * DH);
    const unsigned short* kh = K + head * (SEQ * DH);
    const unsigned short* vh = Vt + head * (DH * SEQ);

    const bf16x8 qf0 = ld_bf8(qh + (m0 + l31) * DH + hi * 8);
    const bf16x8 qf1 = ld_bf8(qh + (m0 + l31) * DH + 16 + hi * 8);

    f32x16 oacc = {0.f, 0.f, 0.f, 0.f, 0.f, 0.f, 0.f, 0.f,
                   0.f, 0.f, 0.f, 0.f, 0.f, 0.f, 0.f, 0.f};
    float ls = 0.f;

    const unsigned short* kp = kh + (kq * 1024 + l31) * DH + hi * 8;
    const unsigned short* vp = vh + l31 * SEQ + kq * 1024 + hi * 8;

    for (int nb = 0; nb < 32; nb++) {
        bf16x8 kc0 = ld_bf8(kp), kc1 = ld_bf8(kp + 16);
        bf16x8 vc0 = ld_bf8(vp), vc1 = ld_bf8(vp + 16);
        attn_step(kc0, kc1, vc0, vc1, qf0, qf1, oacc, ls);
        kp += 32 * DH;
        vp += 32;
        __syncthreads();  // keep all 8 waves on the same K/V window (L1 reuse)
    }

    ls += __shfl_xor(ls, 32);
    const int slot = (head * 128 + qt128) * 4 + kq;
    float* po = pO + slot * 1024 + lane * 16;
#pragma unroll
    for (int g = 0; g < 4; g++) {
        *(f32x4*)(po + 4 * g) =
            (f32x4){oacc[4 * g], oacc[4 * g + 1], oacc[4 * g + 2], oacc[4 * g + 3]};
    }
    if (hi == 0) pls[slot * 32 + l31] = ls;
}

// ---------------- Kernel 2b: combine K-split partials -> An (bf16) ----------------
__global__ __launch_bounds__(256, 4) void combine_kernel(
    const float* __restrict__ pO, const float* __restrict__ pls,
    unsigned short* __restrict__ An) {
    const int lane = threadIdx.x & 63;
    const int w = threadIdx.x >> 6;
    const int l31 = lane & 31;
    const int hi = lane >> 5;
    int b = blockIdx.x;
    b = (b & 7) * 32 + (b >> 3);  // head-per-XCD (partials are L2-local)
    const int qt = b * 4 + w;     // [0,1024)
    const int head = qt >> 7;
    const int m0 = (qt & 127) * 32;

    f32x16 o = {0.f, 0.f, 0.f, 0.f, 0.f, 0.f, 0.f, 0.f,
                0.f, 0.f, 0.f, 0.f, 0.f, 0.f, 0.f, 0.f};
    float ls = 0.f;
#pragma unroll
    for (int kq = 0; kq < 4; kq++) {
        const float* po = pO + (qt * 4 + kq) * 1024 + lane * 16;
#pragma unroll
        for (int g = 0; g < 4; g++) {
            f32x4 v = *(const f32x4*)(po + 4 * g);
            o[4 * g] += v[0];
            o[4 * g + 1] += v[1];
            o[4 * g + 2] += v[2];
            o[4 * g + 3] += v[3];
        }
        ls += pls[(qt * 4 + kq) * 32 + l31];
    }
    const float inv = 1.0f / ls;
    unsigned short* op = An + (m0 + l31) * 256 + head * DH;
#pragma unroll
    for (int g = 0; g < 4; g++) {
        unsigned lo = cvtpk(o[4 * g] * inv, o[4 * g + 1] * inv);
        unsigned hw = cvtpk(o[4 * g + 2] * inv, o[4 * g + 3] * inv);
        *(u32x2*)(op + 8 * g + 4 * hi) = (u32x2){lo, hw};
    }
}

// ---- fallback attn (round-3 style: in-block KSPLIT=4, LDS combine) ----
__global__ __launch_bounds__(256, 4) void attn_fallback_kernel(
    const unsigned short* __restrict__ Q, const unsigned short* __restrict__ K,
    const unsigned short* __restrict__ Vt, unsigned short* __restrict__ An) {
    __shared__ float cO[3][64][17];
    __shared__ float cls[3][32];
    const int lane = threadIdx.x & 63;
    const int w = threadIdx.x >> 6;
    const int l31 = lane & 31;
    const int hi = lane >> 5;

    int bid = blockIdx.x;
    bid = (bid & 7) * 128 + (bid >> 3);
    const int head = bid >> 7;
    const int m0 = (bid & 127) * 32;

    const unsigned short* qh = Q + head * (SEQ * DH);
    const unsigned short* kh = K + head * (SEQ * DH);
    const unsigned short* vh = Vt + head * (DH * SEQ);

    const bf16x8 qf0 = ld_bf8(qh + (m0 + l31) * DH + hi * 8);
    const bf16x8 qf1 = ld_bf8(qh + (m0 + l31) * DH + 16 + hi * 8);

    f32x16 oacc = {0.f, 0.f, 0.f, 0.f, 0.f, 0.f, 0.f, 0.f,
                   0.f, 0.f, 0.f, 0.f, 0.f, 0.f, 0.f, 0.f};
    float ls = 0.f;

    const unsigned short* kp = kh + (w * 1024 + l31) * DH + hi * 8;
    const unsigned short* vp = vh + l31 * SEQ + w * 1024 + hi * 8;

    for (int nb = 0; nb < 32; nb++) {
        bf16x8 kc0 = ld_bf8(kp), kc1 = ld_bf8(kp + 16);
        bf16x8 vc0 = ld_bf8(vp), vc1 = ld_bf8(vp + 16);
        attn_step(kc0, kc1, vc0, vc1, qf0, qf1, oacc, ls);
        kp += 32 * DH;
        vp += 32;
    }

    ls += __shfl_xor(ls, 32);
    if (w > 0) {
#pragma unroll
        for (int i = 0; i < 16; i++) cO[w - 1][lane][i] = oacc[i];
        if (hi == 0) cls[w - 1][l31] = ls;
    }
    __syncthreads();
    if (w == 0) {
#pragma unroll
        for (int j = 0; j < 3; j++) {
#pragma unroll
            for (int i = 0; i < 16; i++) oacc[i] += cO[j][lane][i];
            ls += cls[j][l31];
        }
        const float inv = 1.0f / ls;
        unsigned short* op = An + (m0 + l31) * 256 + head * DH;
#pragma unroll
        for (int g = 0; g < 4; g++) {
            unsigned lo = cvtpk(oacc[4 * g] * inv, oacc[4 * g + 1] * inv);
            unsigned hw = cvtpk(oacc[4 * g + 2] * inv, oacc[4 * g + 3] * inv);
            *(u32x2*)(op + 8 * g + 4 * hi) = (u32x2){lo, hw};
        }
    }
}

// ---------------- Kernel 3: output projection, bf16 Wo ----------------
__global__ __launch_bounds__(256, 4) void oproj_bf16_kernel(
    const unsigned short* __restrict__ An, const unsigned short* __restrict__ Wo,
    float* __restrict__ out) {
    const int lane = threadIdx.x & 63;
    const int w = threadIdx.x >> 6;
    const int cl = lane & 15;
    const int h4 = lane >> 4;
    const int t = blockIdx.x * 4 + w;
    const int m0 = (t >> 4) * 32;
    const int n0 = (t & 15) * 16;

    const unsigned short* ap0 = An + (m0 + cl) * 256 + h4 * 8;
    const unsigned short* ap1 = ap0 + 16 * 256;
    const unsigned short* wb0 = Wo + (n0 + cl) * 256 + h4 * 8;

    f32x4 acc00 = {0.f, 0.f, 0.f, 0.f}, acc10 = {0.f, 0.f, 0.f, 0.f};
#pragma unroll
    for (int ksi = 0; ksi < 8; ksi++) {
        bf16x8 a0 = ld_bf8(ap0 + ksi * 32);
        bf16x8 a1 = ld_bf8(ap1 + ksi * 32);
        bf16x8 b0 = ld_bf8(wb0 + ksi * 32);
        acc00 = MFMA16(a0, b0, acc00, 0, 0, 0);
        acc10 = MFMA16(a1, b0, acc10, 0, 0, 0);
    }
#pragma unroll
    for (int am = 0; am < 2; am++) {
#pragma unroll
        for (int r = 0; r < 4; r++) {
            const int cm = m0 + am * 16 + h4 * 4 + r;
            out[cm * 256 + n0 + cl] = am ? acc10[r] : acc00[r];
        }
    }
}

// ---- fallback oproj (f32 Wo, inline cvt) ----
__global__ __launch_bounds__(256) void oproj_f32_kernel(
    const unsigned short* __restrict__ An, const float* __restrict__ Wo,
    float* __restrict__ out) {
    const int lane = threadIdx.x & 63;
    const int w = threadIdx.x >> 6;
    const int cl = lane & 15;
    const int h4 = lane >> 4;
    const int t = blockIdx.x * 4 + w;
    const int m0 = (t >> 3) * 32;
    const int n0 = (t & 7) * 32;

    const unsigned short* ap0 = An + (m0 + cl) * 256 + h4 * 8;
    const unsigned short* ap1 = ap0 + 16 * 256;
    const float* wb0 = Wo + (n0 + cl) * 256 + h4 * 8;
    const float* wb1 = wb0 + 16 * 256;

    f32x4 acc00 = {0.f, 0.f, 0.f, 0.f}, acc01 = {0.f, 0.f, 0.f, 0.f};
    f32x4 acc10 = {0.f, 0.f, 0.f, 0.f}, acc11 = {0.f, 0.f, 0.f, 0.f};
#pragma unroll
    for (int ksi = 0; ksi < 8; ksi++) {
        bf16x8 a0 = ld_bf8(ap0 + ksi * 32);
        bf16x8 a1 = ld_bf8(ap1 + ksi * 32);
        bf16x8 b0 = cvt_f8(*(const f32x8*)(wb0 + ksi * 32));
        bf16x8 b1 = cvt_f8(*(const f32x8*)(wb1 + ksi * 32));
        acc00 = MFMA16(a0, b0, acc00, 0, 0, 0);
        acc01 = MFMA16(a0, b1, acc01, 0, 0, 0);
        acc10 = MFMA16(a1, b0, acc10, 0, 0, 0);
        acc11 = MFMA16(a1, b1, acc11, 0, 0, 0);
    }
#pragma unroll
    for (int am = 0; am < 2; am++) {
#pragma unroll
        for (int r = 0; r < 4; r++) {
            const int cm = m0 + am * 16 + h4 * 4 + r;
#pragma unroll
            for (int bn = 0; bn < 2; bn++) {
                float v = am ? (bn ? acc11[r] : acc10[r]) : (bn ? acc01[r] : acc00[r]);
                out[cm * 256 + n0 + bn * 16 + cl] = v;
            }
        }
    }
}

extern "C" void kernel_launch(void* const* d_in, const int* in_sizes, int n_in,
                              void* d_out, int out_size, void* d_ws, size_t ws_size,
                              hipStream_t stream) {
    const float* query = (const float*)d_in[0];
    const float* key_ = (const float*)d_in[1];
    const float* value = (const float*)d_in[2];
    const float* radial = (const float*)d_in[3];
    const float* Wq = (const float*)d_in[4];
    const float* Wk = (const float*)d_in[5];
    const float* Wv = (const float*)d_in[6];
    const float* Wo = (const float*)d_in[7];

    const size_t MB = 1u << 20;
    uint8_t* base = (uint8_t*)d_ws;
    unsigned short* wq = (unsigned short*)(base + 0 * MB);
    unsigned short* wk = (unsigned short*)(base + 2 * MB);
    unsigned short* wv = (unsigned short*)(base + 4 * MB);
    unsigned short* wa = (unsigned short*)(base + 6 * MB);

    if (ws_size >= 26 * MB) {
        // full path: precvt + shared-stream attn with cross-block K-split
        unsigned short* bX0 = (unsigned short*)(base + 8 * MB);
        unsigned short* bX1 = (unsigned short*)(base + 10 * MB);
        unsigned short* bX2 = (unsigned short*)(base + 12 * MB);
        float* pO = (float*)(base + 8 * MB);  // 16 MB, reuses bX after proj
        unsigned short* bWq = (unsigned short*)(base + 24 * MB);
        unsigned short* bWk = (unsigned short*)(base + 24 * MB + 128 * 1024);
        unsigned short* bWv = (unsigned short*)(base + 24 * MB + 256 * 1024);
        unsigned short* bWo = (unsigned short*)(base + 24 * MB + 384 * 1024);
        float* pls = (float*)(base + 24 * MB + 512 * 1024);  // 512 KB
        precvt_kernel<<<1664, 256, 0, stream>>>(query, key_, value, Wq, Wk, Wv, Wo,
                                                bX0, bX1, bX2, bWq, bWk, bWv, bWo);
        proj_bf16_kernel<<<dim3(256, 3), 256, 0, stream>>>(bX0, bX1, bX2, bWq, bWk, bWv,
                                                           radial, wq, wk, wv);
        attn_shared_kernel<<<512, 512, 0, stream>>>(wq, wk, wv, pO, pls);
        combine_kernel<<<256, 256, 0, stream>>>(pO, pls, wa);
        oproj_bf16_kernel<<<512, 256, 0, stream>>>(wa, bWo, (float*)d_out);
    } else if (ws_size >= (size_t)(15.5 * 1024 * 1024)) {
        unsigned short* bX0 = (unsigned short*)(base + 8 * MB);
        unsigned short* bX1 = (unsigned short*)(base + 10 * MB);
        unsigned short* bX2 = (unsigned short*)(base + 12 * MB);
        unsigned short* bWq = (unsigned short*)(base + 14 * MB);
        unsigned short* bWk = (unsigned short*)(base + 14 * MB + 128 * 1024);
        unsigned short* bWv = (unsigned short*)(base + 14 * MB + 256 * 1024);
        unsigned short* bWo = (unsigned short*)(base + 14 * MB + 384 * 1024);
        precvt_kernel<<<1664, 256, 0, stream>>>(query, key_, value, Wq, Wk, Wv, Wo,
                                                bX0, bX1, bX2, bWq, bWk, bWv, bWo);
        proj_bf16_kernel<<<dim3(256, 3), 256, 0, stream>>>(bX0, bX1, bX2, bWq, bWk, bWv,
                                                           radial, wq, wk, wv);
        attn_fallback_kernel<<<1024, 256, 0, stream>>>(wq, wk, wv, wa);
        oproj_bf16_kernel<<<512, 256, 0, stream>>>(wa, bWo, (float*)d_out);
    } else {
        proj_f32_kernel<<<dim3(256, 3), 256, 0, stream>>>(query, key_, value, Wq, Wk, Wv,
                                                          radial, wq, wk, wv);
        attn_fallback_kernel<<<1024, 256, 0, stream>>>(wq, wk, wv, wa);
        oproj_f32_kernel<<<256, 256, 0, stream>>>(wa, Wo, (float*)d_out);
    }
}

// Round 7
// 79.177 us; speedup vs baseline: 2.2403x; 1.1504x over previous
//
#include <hip/hip_runtime.h>
#include <cstdint>

#define SEQ 4096
#define NH 8
#define DH 32

typedef __bf16 bf16x8 __attribute__((ext_vector_type(8)));
typedef float f32x4 __attribute__((ext_vector_type(4)));
typedef float f32x8 __attribute__((ext_vector_type(8)));
typedef float f32x16 __attribute__((ext_vector_type(16)));
typedef unsigned short u16x8 __attribute__((ext_vector_type(8)));
typedef unsigned u32x4 __attribute__((ext_vector_type(4)));
typedef unsigned u32x2 __attribute__((ext_vector_type(2)));
typedef int i32x2 __attribute__((ext_vector_type(2)));

#define MFMA16 __builtin_amdgcn_mfma_f32_16x16x32_bf16
#define MFMA32 __builtin_amdgcn_mfma_f32_32x32x16_bf16

#define QSCALE 0.25503902427f /* (1/sqrt(32)) * log2(e) */

__device__ inline bf16x8 ld_bf8(const unsigned short* p) {
    return __builtin_bit_cast(bf16x8, *(const u16x8*)p);
}
__device__ inline unsigned short bfbits(float v) {
    return __builtin_bit_cast(unsigned short, (__bf16)v);
}
__device__ inline bf16x8 cvt_f8(f32x8 v) {
    bf16x8 r;
#pragma unroll
    for (int i = 0; i < 8; i++) r[i] = (__bf16)v[i];
    return r;
}
__device__ inline unsigned cvtpk(float lo, float hi) {
    unsigned r;
    asm("v_cvt_pk_bf16_f32 %0, %1, %2" : "=v"(r) : "v"(lo), "v"(hi));
    return r;
}

// ---------------- Kernel 0: preconvert f32 -> bf16 ----------------
__global__ __launch_bounds__(256) void precvt_kernel(
    const float* __restrict__ x0, const float* __restrict__ x1, const float* __restrict__ x2,
    const float* __restrict__ w0, const float* __restrict__ w1, const float* __restrict__ w2,
    const float* __restrict__ w3,
    unsigned short* __restrict__ bx0, unsigned short* __restrict__ bx1,
    unsigned short* __restrict__ bx2, unsigned short* __restrict__ bw0,
    unsigned short* __restrict__ bw1, unsigned short* __restrict__ bw2,
    unsigned short* __restrict__ bw3) {
    const int i = blockIdx.x * 256 + threadIdx.x;
    const float* src;
    unsigned short* dst;
    int off;
    float scale = 1.0f;
    if (i < 393216) {
        const int sel = i >> 17;
        off = i & 131071;
        src = (sel == 0) ? x0 : (sel == 1) ? x1 : x2;
        dst = (sel == 0) ? bx0 : (sel == 1) ? bx1 : bx2;
        if (sel == 0) scale = QSCALE;
    } else {
        const int j = i - 393216;
        const int sel = j >> 13;
        off = j & 8191;
        src = (sel == 0) ? w0 : (sel == 1) ? w1 : (sel == 2) ? w2 : w3;
        dst = (sel == 0) ? bw0 : (sel == 1) ? bw1 : (sel == 2) ? bw2 : bw3;
    }
    f32x8 v = ((const f32x8*)src)[off];
    u16x8 r;
#pragma unroll
    for (int j = 0; j < 8; j++) r[j] = bfbits(v[j] * scale);
    ((u16x8*)dst)[off] = r;
}

// ---------------- Kernel 1: QKV projections, bf16 inputs ----------------
__global__ __launch_bounds__(256, 4) void proj_bf16_kernel(
    const unsigned short* __restrict__ X0, const unsigned short* __restrict__ X1,
    const unsigned short* __restrict__ X2, const unsigned short* __restrict__ W0,
    const unsigned short* __restrict__ W1, const unsigned short* __restrict__ W2,
    const float* __restrict__ radial,
    unsigned short* __restrict__ outq, unsigned short* __restrict__ outk,
    unsigned short* __restrict__ outv) {
    const int sel = blockIdx.y;
    const unsigned short* X = (sel == 0) ? X0 : (sel == 1) ? X1 : X2;
    const unsigned short* W = (sel == 0) ? W0 : (sel == 1) ? W1 : W2;
    const int lane = threadIdx.x & 63;
    const int w = threadIdx.x >> 6;
    const int cl = lane & 15;
    const int h4 = lane >> 4;
    const int t = blockIdx.x * 4 + w;
    const int m0 = (t >> 3) * 32;
    const int n0 = (t & 7) * 32;

    const unsigned short* xa0 = X + (m0 + cl) * 256 + h4 * 8;
    const unsigned short* xa1 = xa0 + 16 * 256;
    const unsigned short* wb0 = W + (n0 + cl) * 256 + h4 * 8;
    const unsigned short* wb1 = wb0 + 16 * 256;

    f32x4 acc00 = {0.f, 0.f, 0.f, 0.f}, acc01 = {0.f, 0.f, 0.f, 0.f};
    f32x4 acc10 = {0.f, 0.f, 0.f, 0.f}, acc11 = {0.f, 0.f, 0.f, 0.f};
#pragma unroll
    for (int ksi = 0; ksi < 8; ksi++) {
        bf16x8 a0 = ld_bf8(xa0 + ksi * 32);
        bf16x8 a1 = ld_bf8(xa1 + ksi * 32);
        bf16x8 b0 = ld_bf8(wb0 + ksi * 32);
        bf16x8 b1 = ld_bf8(wb1 + ksi * 32);
        acc00 = MFMA16(a0, b0, acc00, 0, 0, 0);
        acc01 = MFMA16(a0, b1, acc01, 0, 0, 0);
        acc10 = MFMA16(a1, b0, acc10, 0, 0, 0);
        acc11 = MFMA16(a1, b1, acc11, 0, 0, 0);
    }

#pragma unroll
    for (int am = 0; am < 2; am++) {
#pragma unroll
        for (int r = 0; r < 4; r++) {
            const int cm = m0 + am * 16 + h4 * 4 + r;
            float rm = (sel == 2) ? radial[cm] : 0.f;
#pragma unroll
            for (int bn = 0; bn < 2; bn++) {
                float v = am ? (bn ? acc11[r] : acc10[r]) : (bn ? acc01[r] : acc00[r]);
                const int cn = n0 + bn * 16 + cl;
                const int h = cn >> 5, d = cn & 31;
                if (sel == 0) outq[(h * SEQ + cm) * DH + d] = bfbits(v);
                else if (sel == 1) outk[(h * SEQ + cm) * DH + d] = bfbits(v);
                else outv[(h * DH + d) * SEQ + cm] = bfbits(v * rm);
            }
        }
    }
}

// ---- fallback (small ws): proj with inline f32->bf16 conversion ----
__global__ __launch_bounds__(256) void proj_f32_kernel(
    const float* __restrict__ X0, const float* __restrict__ X1, const float* __restrict__ X2,
    const float* __restrict__ W0, const float* __restrict__ W1, const float* __restrict__ W2,
    const float* __restrict__ radial,
    unsigned short* __restrict__ outq, unsigned short* __restrict__ outk,
    unsigned short* __restrict__ outv) {
    const int sel = blockIdx.y;
    const float* X = (sel == 0) ? X0 : (sel == 1) ? X1 : X2;
    const float* W = (sel == 0) ? W0 : (sel == 1) ? W1 : W2;
    const int lane = threadIdx.x & 63;
    const int w = threadIdx.x >> 6;
    const int cl = lane & 15;
    const int h4 = lane >> 4;
    const int t = blockIdx.x * 4 + w;
    const int m0 = (t >> 3) * 32;
    const int n0 = (t & 7) * 32;

    const float* xa0 = X + (m0 + cl) * 256 + h4 * 8;
    const float* xa1 = xa0 + 16 * 256;
    const float* wb0 = W + (n0 + cl) * 256 + h4 * 8;
    const float* wb1 = wb0 + 16 * 256;

    f32x4 acc00 = {0.f, 0.f, 0.f, 0.f}, acc01 = {0.f, 0.f, 0.f, 0.f};
    f32x4 acc10 = {0.f, 0.f, 0.f, 0.f}, acc11 = {0.f, 0.f, 0.f, 0.f};
#pragma unroll
    for (int ksi = 0; ksi < 8; ksi++) {
        bf16x8 a0 = cvt_f8(*(const f32x8*)(xa0 + ksi * 32));
        bf16x8 a1 = cvt_f8(*(const f32x8*)(xa1 + ksi * 32));
        bf16x8 b0 = cvt_f8(*(const f32x8*)(wb0 + ksi * 32));
        bf16x8 b1 = cvt_f8(*(const f32x8*)(wb1 + ksi * 32));
        acc00 = MFMA16(a0, b0, acc00, 0, 0, 0);
        acc01 = MFMA16(a0, b1, acc01, 0, 0, 0);
        acc10 = MFMA16(a1, b0, acc10, 0, 0, 0);
        acc11 = MFMA16(a1, b1, acc11, 0, 0, 0);
    }
#pragma unroll
    for (int am = 0; am < 2; am++) {
#pragma unroll
        for (int r = 0; r < 4; r++) {
            const int cm = m0 + am * 16 + h4 * 4 + r;
            float rm = (sel == 2) ? radial[cm] : 0.f;
#pragma unroll
            for (int bn = 0; bn < 2; bn++) {
                float v = am ? (bn ? acc11[r] : acc10[r]) : (bn ? acc01[r] : acc00[r]);
                const int cn = n0 + bn * 16 + cl;
                const int h = cn >> 5, d = cn & 31;
                if (sel == 0) outq[(h * SEQ + cm) * DH + d] = bfbits(v * QSCALE);
                else if (sel == 1) outk[(h * SEQ + cm) * DH + d] = bfbits(v);
                else outv[(h * DH + d) * SEQ + cm] = bfbits(v * rm);
            }
        }
    }
}

// ---------------- attention pieces (split so two chains interleave) ----------------
__device__ inline f32x16 qk_step(bf16x8 kf0, bf16x8 kf1, const bf16x8& qf0,
                                 const bf16x8& qf1) {
    f32x16 s = {0.f, 0.f, 0.f, 0.f, 0.f, 0.f, 0.f, 0.f,
                0.f, 0.f, 0.f, 0.f, 0.f, 0.f, 0.f, 0.f};
    __builtin_amdgcn_s_setprio(1);
    s = MFMA32(kf0, qf0, s, 0, 0, 0);
    s = MFMA32(kf1, qf1, s, 0, 0, 0);
    __builtin_amdgcn_s_setprio(0);
    return s;
}

__device__ inline void sm_pv_step(const f32x16& s, bf16x8 vt0, bf16x8 vt1,
                                  f32x16& oacc, float& ls) {
    float p[16];
#pragma unroll
    for (int r = 0; r < 16; r++) p[r] = __builtin_amdgcn_exp2f(s[r]);
    {
        float s01 = p[0] + p[1], s23 = p[2] + p[3], s45 = p[4] + p[5], s67 = p[6] + p[7];
        float s89 = p[8] + p[9], sab = p[10] + p[11], scd = p[12] + p[13], sef = p[14] + p[15];
        ls += ((s01 + s23) + (s45 + s67)) + ((s89 + sab) + (scd + sef));
    }
    unsigned a01 = cvtpk(p[0], p[1]), a23 = cvtpk(p[2], p[3]);
    unsigned a45 = cvtpk(p[4], p[5]), a67 = cvtpk(p[6], p[7]);
    i32x2 r0 = __builtin_amdgcn_permlane32_swap((int)a01, (int)a45, false, false);
    i32x2 r1 = __builtin_amdgcn_permlane32_swap((int)a23, (int)a67, false, false);
    u32x4 pb0w = {(unsigned)r0[0], (unsigned)r1[0], (unsigned)r0[1], (unsigned)r1[1]};
    unsigned a89 = cvtpk(p[8], p[9]), aab = cvtpk(p[10], p[11]);
    unsigned acd = cvtpk(p[12], p[13]), aef = cvtpk(p[14], p[15]);
    i32x2 r2 = __builtin_amdgcn_permlane32_swap((int)a89, (int)acd, false, false);
    i32x2 r3 = __builtin_amdgcn_permlane32_swap((int)aab, (int)aef, false, false);
    u32x4 pb1w = {(unsigned)r2[0], (unsigned)r3[0], (unsigned)r2[1], (unsigned)r3[1]};
    __builtin_amdgcn_s_setprio(1);
    oacc = MFMA32(vt0, __builtin_bit_cast(bf16x8, pb0w), oacc, 0, 0, 0);
    oacc = MFMA32(vt1, __builtin_bit_cast(bf16x8, pb1w), oacc, 0, 0, 0);
    __builtin_amdgcn_s_setprio(0);
}

// ---------------- Kernel 2: flash attention, ILP=2 ----------------
// Block = 256 thr = 4 waves = one 32-row q-tile; wave w owns keys
// [w*1024,(w+1)*1024) as 16 iters x 64 keys = TWO independent 32-key chains
// interleaved: while chain A's softmax runs on the VALU, chain B's QK MFMAs
// are in the matrix pipe, and vice versa. Attacks the measured latency bound
// (all structures r2-r6 plateaued ~50 us with both pipes <30% busy).
__global__ __launch_bounds__(256, 4) void attn_kernel(
    const unsigned short* __restrict__ Q, const unsigned short* __restrict__ K,
    const unsigned short* __restrict__ Vt, unsigned short* __restrict__ An) {
    __shared__ float cO[3][64][17];
    __shared__ float cls[3][32];
    const int lane = threadIdx.x & 63;
    const int w = threadIdx.x >> 6;  // key-quarter 0..3
    const int l31 = lane & 31;
    const int hi = lane >> 5;

    // head-per-XCD remap: 1024 blocks head-major
    int bid = blockIdx.x;
    bid = (bid & 7) * 128 + (bid >> 3);
    const int head = bid >> 7;
    const int m0 = (bid & 127) * 32;

    const unsigned short* qh = Q + head * (SEQ * DH);
    const unsigned short* kh = K + head * (SEQ * DH);
    const unsigned short* vh = Vt + head * (DH * SEQ);

    const bf16x8 qf0 = ld_bf8(qh + (m0 + l31) * DH + hi * 8);
    const bf16x8 qf1 = ld_bf8(qh + (m0 + l31) * DH + 16 + hi * 8);

    f32x16 oacc = {0.f, 0.f, 0.f, 0.f, 0.f, 0.f, 0.f, 0.f,
                   0.f, 0.f, 0.f, 0.f, 0.f, 0.f, 0.f, 0.f};
    float ls = 0.f;

    const unsigned short* kp = kh + (w * 1024 + l31) * DH + hi * 8;
    const unsigned short* vp = vh + l31 * SEQ + w * 1024 + hi * 8;

#pragma unroll 2
    for (int nb = 0; nb < 16; nb++) {
        // chain A: keys [n0, n0+32); chain B: keys [n0+32, n0+64)
        bf16x8 kA0 = ld_bf8(kp), kA1 = ld_bf8(kp + 16);
        bf16x8 kB0 = ld_bf8(kp + 1024), kB1 = ld_bf8(kp + 1040);
        bf16x8 vA0 = ld_bf8(vp), vA1 = ld_bf8(vp + 16);
        bf16x8 vB0 = ld_bf8(vp + 32), vB1 = ld_bf8(vp + 48);
        f32x16 sA = qk_step(kA0, kA1, qf0, qf1);
        f32x16 sB = qk_step(kB0, kB1, qf0, qf1);
        sm_pv_step(sA, vA0, vA1, oacc, ls);   // B's QK MFMAs overlap this VALU
        sm_pv_step(sB, vB0, vB1, oacc, ls);   // A's PV MFMAs overlap this VALU
        kp += 64 * DH;
        vp += 64;
    }

    ls += __shfl_xor(ls, 32);
    if (w > 0) {
#pragma unroll
        for (int i = 0; i < 16; i++) cO[w - 1][lane][i] = oacc[i];
        if (hi == 0) cls[w - 1][l31] = ls;
    }
    __syncthreads();
    if (w == 0) {
#pragma unroll
        for (int j = 0; j < 3; j++) {
#pragma unroll
            for (int i = 0; i < 16; i++) oacc[i] += cO[j][lane][i];
            ls += cls[j][l31];
        }
        const float inv = 1.0f / ls;
        unsigned short* op = An + (m0 + l31) * 256 + head * DH;
#pragma unroll
        for (int g = 0; g < 4; g++) {
            unsigned lo = cvtpk(oacc[4 * g] * inv, oacc[4 * g + 1] * inv);
            unsigned hw = cvtpk(oacc[4 * g + 2] * inv, oacc[4 * g + 3] * inv);
            *(u32x2*)(op + 8 * g + 4 * hi) = (u32x2){lo, hw};
        }
    }
}

// ---------------- Kernel 3: output projection, bf16 Wo ----------------
__global__ __launch_bounds__(256, 4) void oproj_bf16_kernel(
    const unsigned short* __restrict__ An, const unsigned short* __restrict__ Wo,
    float* __restrict__ out) {
    const int lane = threadIdx.x & 63;
    const int w = threadIdx.x >> 6;
    const int cl = lane & 15;
    const int h4 = lane >> 4;
    const int t = blockIdx.x * 4 + w;
    const int m0 = (t >> 4) * 32;
    const int n0 = (t & 15) * 16;

    const unsigned short* ap0 = An + (m0 + cl) * 256 + h4 * 8;
    const unsigned short* ap1 = ap0 + 16 * 256;
    const unsigned short* wb0 = Wo + (n0 + cl) * 256 + h4 * 8;

    f32x4 acc00 = {0.f, 0.f, 0.f, 0.f}, acc10 = {0.f, 0.f, 0.f, 0.f};
#pragma unroll
    for (int ksi = 0; ksi < 8; ksi++) {
        bf16x8 a0 = ld_bf8(ap0 + ksi * 32);
        bf16x8 a1 = ld_bf8(ap1 + ksi * 32);
        bf16x8 b0 = ld_bf8(wb0 + ksi * 32);
        acc00 = MFMA16(a0, b0, acc00, 0, 0, 0);
        acc10 = MFMA16(a1, b0, acc10, 0, 0, 0);
    }
#pragma unroll
    for (int am = 0; am < 2; am++) {
#pragma unroll
        for (int r = 0; r < 4; r++) {
            const int cm = m0 + am * 16 + h4 * 4 + r;
            out[cm * 256 + n0 + cl] = am ? acc10[r] : acc00[r];
        }
    }
}

// ---- fallback oproj (f32 Wo, inline cvt) ----
__global__ __launch_bounds__(256) void oproj_f32_kernel(
    const unsigned short* __restrict__ An, const float* __restrict__ Wo,
    float* __restrict__ out) {
    const int lane = threadIdx.x & 63;
    const int w = threadIdx.x >> 6;
    const int cl = lane & 15;
    const int h4 = lane >> 4;
    const int t = blockIdx.x * 4 + w;
    const int m0 = (t >> 3) * 32;
    const int n0 = (t & 7) * 32;

    const unsigned short* ap0 = An + (m0 + cl) * 256 + h4 * 8;
    const unsigned short* ap1 = ap0 + 16 * 256;
    const float* wb0 = Wo + (n0 + cl) * 256 + h4 * 8;
    const float* wb1 = wb0 + 16 * 256;

    f32x4 acc00 = {0.f, 0.f, 0.f, 0.f}, acc01 = {0.f, 0.f, 0.f, 0.f};
    f32x4 acc10 = {0.f, 0.f, 0.f, 0.f}, acc11 = {0.f, 0.f, 0.f, 0.f};
#pragma unroll
    for (int ksi = 0; ksi < 8; ksi++) {
        bf16x8 a0 = ld_bf8(ap0 + ksi * 32);
        bf16x8 a1 = ld_bf8(ap1 + ksi * 32);
        bf16x8 b0 = cvt_f8(*(const f32x8*)(wb0 + ksi * 32));
        bf16x8 b1 = cvt_f8(*(const f32x8*)(wb1 + ksi * 32));
        acc00 = MFMA16(a0, b0, acc00, 0, 0, 0);
        acc01 = MFMA16(a0, b1, acc01, 0, 0, 0);
        acc10 = MFMA16(a1, b0, acc10, 0, 0, 0);
        acc11 = MFMA16(a1, b1, acc11, 0, 0, 0);
    }
#pragma unroll
    for (int am = 0; am < 2; am++) {
#pragma unroll
        for (int r = 0; r < 4; r++) {
            const int cm = m0 + am * 16 + h4 * 4 + r;
#pragma unroll
            for (int bn = 0; bn < 2; bn++) {
                float v = am ? (bn ? acc11[r] : acc10[r]) : (bn ? acc01[r] : acc00[r]);
                out[cm * 256 + n0 + bn * 16 + cl] = v;
            }
        }
    }
}

extern "C" void kernel_launch(void* const* d_in, const int* in_sizes, int n_in,
                              void* d_out, int out_size, void* d_ws, size_t ws_size,
                              hipStream_t stream) {
    const float* query = (const float*)d_in[0];
    const float* key_ = (const float*)d_in[1];
    const float* value = (const float*)d_in[2];
    const float* radial = (const float*)d_in[3];
    const float* Wq = (const float*)d_in[4];
    const float* Wk = (const float*)d_in[5];
    const float* Wv = (const float*)d_in[6];
    const float* Wo = (const float*)d_in[7];

    const size_t MB = 1u << 20;
    uint8_t* base = (uint8_t*)d_ws;
    unsigned short* wq = (unsigned short*)(base + 0 * MB);
    unsigned short* wk = (unsigned short*)(base + 2 * MB);
    unsigned short* wv = (unsigned short*)(base + 4 * MB);
    unsigned short* wa = (unsigned short*)(base + 6 * MB);

    if (ws_size >= (size_t)(15.5 * 1024 * 1024)) {
        unsigned short* bX0 = (unsigned short*)(base + 8 * MB);
        unsigned short* bX1 = (unsigned short*)(base + 10 * MB);
        unsigned short* bX2 = (unsigned short*)(base + 12 * MB);
        unsigned short* bWq = (unsigned short*)(base + 14 * MB);
        unsigned short* bWk = (unsigned short*)(base + 14 * MB + 128 * 1024);
        unsigned short* bWv = (unsigned short*)(base + 14 * MB + 256 * 1024);
        unsigned short* bWo = (unsigned short*)(base + 14 * MB + 384 * 1024);
        precvt_kernel<<<1664, 256, 0, stream>>>(query, key_, value, Wq, Wk, Wv, Wo,
                                                bX0, bX1, bX2, bWq, bWk, bWv, bWo);
        proj_bf16_kernel<<<dim3(256, 3), 256, 0, stream>>>(bX0, bX1, bX2, bWq, bWk, bWv,
                                                           radial, wq, wk, wv);
        attn_kernel<<<1024, 256, 0, stream>>>(wq, wk, wv, wa);
        oproj_bf16_kernel<<<512, 256, 0, stream>>>(wa, bWo, (float*)d_out);
    } else {
        proj_f32_kernel<<<dim3(256, 3), 256, 0, stream>>>(query, key_, value, Wq, Wk, Wv,
                                                          radial, wq, wk, wv);
        attn_kernel<<<1024, 256, 0, stream>>>(wq, wk, wv, wa);
        oproj_f32_kernel<<<256, 256, 0, stream>>>(wa, Wo, (float*)d_out);
    }
}

// Round 8
// 61.894 us; speedup vs baseline: 2.8658x; 1.2792x over previous
//
#include <hip/hip_runtime.h>
#include <cstdint>

#define SEQ 4096
#define NH 8
#define DH 32

typedef __bf16 bf16x8 __attribute__((ext_vector_type(8)));
typedef float f32x4 __attribute__((ext_vector_type(4)));
typedef float f32x8 __attribute__((ext_vector_type(8)));
typedef float f32x16 __attribute__((ext_vector_type(16)));
typedef unsigned short u16x8 __attribute__((ext_vector_type(8)));
typedef unsigned u32x4 __attribute__((ext_vector_type(4)));
typedef unsigned u32x2 __attribute__((ext_vector_type(2)));
typedef int i32x2 __attribute__((ext_vector_type(2)));

#define MFMA16 __builtin_amdgcn_mfma_f32_16x16x32_bf16
#define MFMA32 __builtin_amdgcn_mfma_f32_32x32x16_bf16

#define QSCALE 0.25503902427f /* (1/sqrt(32)) * log2(e) */

__device__ inline bf16x8 ld_bf8(const unsigned short* p) {
    return __builtin_bit_cast(bf16x8, *(const u16x8*)p);
}
__device__ inline unsigned short bfbits(float v) {
    return __builtin_bit_cast(unsigned short, (__bf16)v);
}
__device__ inline bf16x8 cvt_f8(f32x8 v) {
    bf16x8 r;
#pragma unroll
    for (int i = 0; i < 8; i++) r[i] = (__bf16)v[i];
    return r;
}
__device__ inline unsigned cvtpk(float lo, float hi) {
    unsigned r;
    asm("v_cvt_pk_bf16_f32 %0, %1, %2" : "=v"(r) : "v"(lo), "v"(hi));
    return r;
}

// ---------------- Kernel 0: preconvert f32 -> bf16 ----------------
__global__ __launch_bounds__(256) void precvt_kernel(
    const float* __restrict__ x0, const float* __restrict__ x1, const float* __restrict__ x2,
    const float* __restrict__ w0, const float* __restrict__ w1, const float* __restrict__ w2,
    const float* __restrict__ w3,
    unsigned short* __restrict__ bx0, unsigned short* __restrict__ bx1,
    unsigned short* __restrict__ bx2, unsigned short* __restrict__ bw0,
    unsigned short* __restrict__ bw1, unsigned short* __restrict__ bw2,
    unsigned short* __restrict__ bw3) {
    const int i = blockIdx.x * 256 + threadIdx.x;
    const float* src;
    unsigned short* dst;
    int off;
    float scale = 1.0f;
    if (i < 393216) {
        const int sel = i >> 17;
        off = i & 131071;
        src = (sel == 0) ? x0 : (sel == 1) ? x1 : x2;
        dst = (sel == 0) ? bx0 : (sel == 1) ? bx1 : bx2;
        if (sel == 0) scale = QSCALE;
    } else {
        const int j = i - 393216;
        const int sel = j >> 13;
        off = j & 8191;
        src = (sel == 0) ? w0 : (sel == 1) ? w1 : (sel == 2) ? w2 : w3;
        dst = (sel == 0) ? bw0 : (sel == 1) ? bw1 : (sel == 2) ? bw2 : bw3;
    }
    f32x8 v = ((const f32x8*)src)[off];
    u16x8 r;
#pragma unroll
    for (int j = 0; j < 8; j++) r[j] = bfbits(v[j] * scale);
    ((u16x8*)dst)[off] = r;
}

// ---------------- Kernel 1: QKV projections, bf16 inputs ----------------
__global__ __launch_bounds__(256, 4) void proj_bf16_kernel(
    const unsigned short* __restrict__ X0, const unsigned short* __restrict__ X1,
    const unsigned short* __restrict__ X2, const unsigned short* __restrict__ W0,
    const unsigned short* __restrict__ W1, const unsigned short* __restrict__ W2,
    const float* __restrict__ radial,
    unsigned short* __restrict__ outq, unsigned short* __restrict__ outk,
    unsigned short* __restrict__ outv) {
    const int sel = blockIdx.y;
    const unsigned short* X = (sel == 0) ? X0 : (sel == 1) ? X1 : X2;
    const unsigned short* W = (sel == 0) ? W0 : (sel == 1) ? W1 : W2;
    const int lane = threadIdx.x & 63;
    const int w = threadIdx.x >> 6;
    const int cl = lane & 15;
    const int h4 = lane >> 4;
    const int t = blockIdx.x * 4 + w;
    const int m0 = (t >> 3) * 32;
    const int n0 = (t & 7) * 32;

    const unsigned short* xa0 = X + (m0 + cl) * 256 + h4 * 8;
    const unsigned short* xa1 = xa0 + 16 * 256;
    const unsigned short* wb0 = W + (n0 + cl) * 256 + h4 * 8;
    const unsigned short* wb1 = wb0 + 16 * 256;

    f32x4 acc00 = {0.f, 0.f, 0.f, 0.f}, acc01 = {0.f, 0.f, 0.f, 0.f};
    f32x4 acc10 = {0.f, 0.f, 0.f, 0.f}, acc11 = {0.f, 0.f, 0.f, 0.f};
#pragma unroll
    for (int ksi = 0; ksi < 8; ksi++) {
        bf16x8 a0 = ld_bf8(xa0 + ksi * 32);
        bf16x8 a1 = ld_bf8(xa1 + ksi * 32);
        bf16x8 b0 = ld_bf8(wb0 + ksi * 32);
        bf16x8 b1 = ld_bf8(wb1 + ksi * 32);
        acc00 = MFMA16(a0, b0, acc00, 0, 0, 0);
        acc01 = MFMA16(a0, b1, acc01, 0, 0, 0);
        acc10 = MFMA16(a1, b0, acc10, 0, 0, 0);
        acc11 = MFMA16(a1, b1, acc11, 0, 0, 0);
    }

#pragma unroll
    for (int am = 0; am < 2; am++) {
#pragma unroll
        for (int r = 0; r < 4; r++) {
            const int cm = m0 + am * 16 + h4 * 4 + r;
            float rm = (sel == 2) ? radial[cm] : 0.f;
#pragma unroll
            for (int bn = 0; bn < 2; bn++) {
                float v = am ? (bn ? acc11[r] : acc10[r]) : (bn ? acc01[r] : acc00[r]);
                const int cn = n0 + bn * 16 + cl;
                const int h = cn >> 5, d = cn & 31;
                if (sel == 0) outq[(h * SEQ + cm) * DH + d] = bfbits(v);
                else if (sel == 1) outk[(h * SEQ + cm) * DH + d] = bfbits(v);
                else outv[(h * DH + d) * SEQ + cm] = bfbits(v * rm);
            }
        }
    }
}

// ---- fallback (small ws): proj with inline f32->bf16 conversion ----
__global__ __launch_bounds__(256) void proj_f32_kernel(
    const float* __restrict__ X0, const float* __restrict__ X1, const float* __restrict__ X2,
    const float* __restrict__ W0, const float* __restrict__ W1, const float* __restrict__ W2,
    const float* __restrict__ radial,
    unsigned short* __restrict__ outq, unsigned short* __restrict__ outk,
    unsigned short* __restrict__ outv) {
    const int sel = blockIdx.y;
    const float* X = (sel == 0) ? X0 : (sel == 1) ? X1 : X2;
    const float* W = (sel == 0) ? W0 : (sel == 1) ? W1 : W2;
    const int lane = threadIdx.x & 63;
    const int w = threadIdx.x >> 6;
    const int cl = lane & 15;
    const int h4 = lane >> 4;
    const int t = blockIdx.x * 4 + w;
    const int m0 = (t >> 3) * 32;
    const int n0 = (t & 7) * 32;

    const float* xa0 = X + (m0 + cl) * 256 + h4 * 8;
    const float* xa1 = xa0 + 16 * 256;
    const float* wb0 = W + (n0 + cl) * 256 + h4 * 8;
    const float* wb1 = wb0 + 16 * 256;

    f32x4 acc00 = {0.f, 0.f, 0.f, 0.f}, acc01 = {0.f, 0.f, 0.f, 0.f};
    f32x4 acc10 = {0.f, 0.f, 0.f, 0.f}, acc11 = {0.f, 0.f, 0.f, 0.f};
#pragma unroll
    for (int ksi = 0; ksi < 8; ksi++) {
        bf16x8 a0 = cvt_f8(*(const f32x8*)(xa0 + ksi * 32));
        bf16x8 a1 = cvt_f8(*(const f32x8*)(xa1 + ksi * 32));
        bf16x8 b0 = cvt_f8(*(const f32x8*)(wb0 + ksi * 32));
        bf16x8 b1 = cvt_f8(*(const f32x8*)(wb1 + ksi * 32));
        acc00 = MFMA16(a0, b0, acc00, 0, 0, 0);
        acc01 = MFMA16(a0, b1, acc01, 0, 0, 0);
        acc10 = MFMA16(a1, b0, acc10, 0, 0, 0);
        acc11 = MFMA16(a1, b1, acc11, 0, 0, 0);
    }
#pragma unroll
    for (int am = 0; am < 2; am++) {
#pragma unroll
        for (int r = 0; r < 4; r++) {
            const int cm = m0 + am * 16 + h4 * 4 + r;
            float rm = (sel == 2) ? radial[cm] : 0.f;
#pragma unroll
            for (int bn = 0; bn < 2; bn++) {
                float v = am ? (bn ? acc11[r] : acc10[r]) : (bn ? acc01[r] : acc00[r]);
                const int cn = n0 + bn * 16 + cl;
                const int h = cn >> 5, d = cn & 31;
                if (sel == 0) outq[(h * SEQ + cm) * DH + d] = bfbits(v * QSCALE);
                else if (sel == 1) outk[(h * SEQ + cm) * DH + d] = bfbits(v);
                else outv[(h * DH + d) * SEQ + cm] = bfbits(v * rm);
            }
        }
    }
}

// ---------------- attention pieces ----------------
__device__ inline f32x16 qk_step(bf16x8 kf0, bf16x8 kf1, const bf16x8& qf0,
                                 const bf16x8& qf1) {
    f32x16 s = {0.f, 0.f, 0.f, 0.f, 0.f, 0.f, 0.f, 0.f,
                0.f, 0.f, 0.f, 0.f, 0.f, 0.f, 0.f, 0.f};
    __builtin_amdgcn_s_setprio(1);
    s = MFMA32(kf0, qf0, s, 0, 0, 0);
    s = MFMA32(kf1, qf1, s, 0, 0, 0);
    __builtin_amdgcn_s_setprio(0);
    return s;
}

__device__ inline void sm_pv_step(const f32x16& s, bf16x8 vt0, bf16x8 vt1,
                                  f32x16& oacc, float& ls) {
    float p[16];
#pragma unroll
    for (int r = 0; r < 16; r++) p[r] = __builtin_amdgcn_exp2f(s[r]);
    {
        float s01 = p[0] + p[1], s23 = p[2] + p[3], s45 = p[4] + p[5], s67 = p[6] + p[7];
        float s89 = p[8] + p[9], sab = p[10] + p[11], scd = p[12] + p[13], sef = p[14] + p[15];
        ls += ((s01 + s23) + (s45 + s67)) + ((s89 + sab) + (scd + sef));
    }
    unsigned a01 = cvtpk(p[0], p[1]), a23 = cvtpk(p[2], p[3]);
    unsigned a45 = cvtpk(p[4], p[5]), a67 = cvtpk(p[6], p[7]);
    i32x2 r0 = __builtin_amdgcn_permlane32_swap((int)a01, (int)a45, false, false);
    i32x2 r1 = __builtin_amdgcn_permlane32_swap((int)a23, (int)a67, false, false);
    u32x4 pb0w = {(unsigned)r0[0], (unsigned)r1[0], (unsigned)r0[1], (unsigned)r1[1]};
    unsigned a89 = cvtpk(p[8], p[9]), aab = cvtpk(p[10], p[11]);
    unsigned acd = cvtpk(p[12], p[13]), aef = cvtpk(p[14], p[15]);
    i32x2 r2 = __builtin_amdgcn_permlane32_swap((int)a89, (int)acd, false, false);
    i32x2 r3 = __builtin_amdgcn_permlane32_swap((int)aab, (int)aef, false, false);
    u32x4 pb1w = {(unsigned)r2[0], (unsigned)r3[0], (unsigned)r2[1], (unsigned)r3[1]};
    __builtin_amdgcn_s_setprio(1);
    oacc = MFMA32(vt0, __builtin_bit_cast(bf16x8, pb0w), oacc, 0, 0, 0);
    oacc = MFMA32(vt1, __builtin_bit_cast(bf16x8, pb1w), oacc, 0, 0, 0);
    __builtin_amdgcn_s_setprio(0);
}

// ---------------- Kernel 2: flash attention, 64 q-rows per wave ----------------
// Block = 512 thr = 8 waves = ONE 64-row q-group x 8 key-eighths (512 keys,
// 16 iters). Each wave computes TWO independent 32-q halves (A,B) against the
// SAME K/V fragments: halves wave-iteration count (131k -> 65.5k) and halves
// K/V L2 traffic, attacking the measured per-iteration latency law directly.
// LDS combine of the 8 K-split partials at the end.
__global__ __launch_bounds__(512, 4) void attn_kernel(
    const unsigned short* __restrict__ Q, const unsigned short* __restrict__ K,
    const unsigned short* __restrict__ Vt, unsigned short* __restrict__ An) {
    __shared__ float cO[7][2][64][17];
    __shared__ float cls[7][2][32];
    const int lane = threadIdx.x & 63;
    const int w = threadIdx.x >> 6;  // key-eighth 0..7
    const int l31 = lane & 31;
    const int hi = lane >> 5;

    // head-per-XCD remap: 512 blocks head-major (bijective: 512 = 8*64)
    int bid = blockIdx.x;
    bid = (bid & 7) * 64 + (bid >> 3);
    const int head = bid >> 6;
    const int m0 = (bid & 63) * 64;  // 64 q-rows per block

    const unsigned short* qh = Q + head * (SEQ * DH);
    const unsigned short* kh = K + head * (SEQ * DH);
    const unsigned short* vh = Vt + head * (DH * SEQ);

    const bf16x8 qA0 = ld_bf8(qh + (m0 + l31) * DH + hi * 8);
    const bf16x8 qA1 = ld_bf8(qh + (m0 + l31) * DH + 16 + hi * 8);
    const bf16x8 qB0 = ld_bf8(qh + (m0 + 32 + l31) * DH + hi * 8);
    const bf16x8 qB1 = ld_bf8(qh + (m0 + 32 + l31) * DH + 16 + hi * 8);

    f32x16 oA = {0.f, 0.f, 0.f, 0.f, 0.f, 0.f, 0.f, 0.f,
                 0.f, 0.f, 0.f, 0.f, 0.f, 0.f, 0.f, 0.f};
    f32x16 oB = {0.f, 0.f, 0.f, 0.f, 0.f, 0.f, 0.f, 0.f,
                 0.f, 0.f, 0.f, 0.f, 0.f, 0.f, 0.f, 0.f};
    float lsA = 0.f, lsB = 0.f;

    const unsigned short* kp = kh + (w * 512 + l31) * DH + hi * 8;
    const unsigned short* vp = vh + l31 * SEQ + w * 512 + hi * 8;

    for (int nb = 0; nb < 16; nb++) {
        bf16x8 kc0 = ld_bf8(kp), kc1 = ld_bf8(kp + 16);
        bf16x8 vc0 = ld_bf8(vp), vc1 = ld_bf8(vp + 16);
        f32x16 sA = qk_step(kc0, kc1, qA0, qA1);
        sm_pv_step(sA, vc0, vc1, oA, lsA);
        f32x16 sB = qk_step(kc0, kc1, qB0, qB1);
        sm_pv_step(sB, vc0, vc1, oB, lsB);
        kp += 32 * DH;
        vp += 32;
    }

    lsA += __shfl_xor(lsA, 32);
    lsB += __shfl_xor(lsB, 32);
    if (w > 0) {
#pragma unroll
        for (int i = 0; i < 16; i++) {
            cO[w - 1][0][lane][i] = oA[i];
            cO[w - 1][1][lane][i] = oB[i];
        }
        if (hi == 0) {
            cls[w - 1][0][l31] = lsA;
            cls[w - 1][1][l31] = lsB;
        }
    }
    __syncthreads();
    if (w == 0) {
#pragma unroll
        for (int j = 0; j < 7; j++) {
#pragma unroll
            for (int i = 0; i < 16; i++) {
                oA[i] += cO[j][0][lane][i];
                oB[i] += cO[j][1][lane][i];
            }
            lsA += cls[j][0][l31];
            lsB += cls[j][1][l31];
        }
        const float invA = 1.0f / lsA;
        const float invB = 1.0f / lsB;
        unsigned short* opA = An + (m0 + l31) * 256 + head * DH;
        unsigned short* opB = An + (m0 + 32 + l31) * 256 + head * DH;
#pragma unroll
        for (int g = 0; g < 4; g++) {
            unsigned loA = cvtpk(oA[4 * g] * invA, oA[4 * g + 1] * invA);
            unsigned hwA = cvtpk(oA[4 * g + 2] * invA, oA[4 * g + 3] * invA);
            *(u32x2*)(opA + 8 * g + 4 * hi) = (u32x2){loA, hwA};
            unsigned loB = cvtpk(oB[4 * g] * invB, oB[4 * g + 1] * invB);
            unsigned hwB = cvtpk(oB[4 * g + 2] * invB, oB[4 * g + 3] * invB);
            *(u32x2*)(opB + 8 * g + 4 * hi) = (u32x2){loB, hwB};
        }
    }
}

// ---------------- Kernel 3: output projection, bf16 Wo ----------------
__global__ __launch_bounds__(256, 4) void oproj_bf16_kernel(
    const unsigned short* __restrict__ An, const unsigned short* __restrict__ Wo,
    float* __restrict__ out) {
    const int lane = threadIdx.x & 63;
    const int w = threadIdx.x >> 6;
    const int cl = lane & 15;
    const int h4 = lane >> 4;
    const int t = blockIdx.x * 4 + w;
    const int m0 = (t >> 4) * 32;
    const int n0 = (t & 15) * 16;

    const unsigned short* ap0 = An + (m0 + cl) * 256 + h4 * 8;
    const unsigned short* ap1 = ap0 + 16 * 256;
    const unsigned short* wb0 = Wo + (n0 + cl) * 256 + h4 * 8;

    f32x4 acc00 = {0.f, 0.f, 0.f, 0.f}, acc10 = {0.f, 0.f, 0.f, 0.f};
#pragma unroll
    for (int ksi = 0; ksi < 8; ksi++) {
        bf16x8 a0 = ld_bf8(ap0 + ksi * 32);
        bf16x8 a1 = ld_bf8(ap1 + ksi * 32);
        bf16x8 b0 = ld_bf8(wb0 + ksi * 32);
        acc00 = MFMA16(a0, b0, acc00, 0, 0, 0);
        acc10 = MFMA16(a1, b0, acc10, 0, 0, 0);
    }
#pragma unroll
    for (int am = 0; am < 2; am++) {
#pragma unroll
        for (int r = 0; r < 4; r++) {
            const int cm = m0 + am * 16 + h4 * 4 + r;
            out[cm * 256 + n0 + cl] = am ? acc10[r] : acc00[r];
        }
    }
}

// ---- fallback oproj (f32 Wo, inline cvt) ----
__global__ __launch_bounds__(256) void oproj_f32_kernel(
    const unsigned short* __restrict__ An, const float* __restrict__ Wo,
    float* __restrict__ out) {
    const int lane = threadIdx.x & 63;
    const int w = threadIdx.x >> 6;
    const int cl = lane & 15;
    const int h4 = lane >> 4;
    const int t = blockIdx.x * 4 + w;
    const int m0 = (t >> 3) * 32;
    const int n0 = (t & 7) * 32;

    const unsigned short* ap0 = An + (m0 + cl) * 256 + h4 * 8;
    const unsigned short* ap1 = ap0 + 16 * 256;
    const float* wb0 = Wo + (n0 + cl) * 256 + h4 * 8;
    const float* wb1 = wb0 + 16 * 256;

    f32x4 acc00 = {0.f, 0.f, 0.f, 0.f}, acc01 = {0.f, 0.f, 0.f, 0.f};
    f32x4 acc10 = {0.f, 0.f, 0.f, 0.f}, acc11 = {0.f, 0.f, 0.f, 0.f};
#pragma unroll
    for (int ksi = 0; ksi < 8; ksi++) {
        bf16x8 a0 = ld_bf8(ap0 + ksi * 32);
        bf16x8 a1 = ld_bf8(ap1 + ksi * 32);
        bf16x8 b0 = cvt_f8(*(const f32x8*)(wb0 + ksi * 32));
        bf16x8 b1 = cvt_f8(*(const f32x8*)(wb1 + ksi * 32));
        acc00 = MFMA16(a0, b0, acc00, 0, 0, 0);
        acc01 = MFMA16(a0, b1, acc01, 0, 0, 0);
        acc10 = MFMA16(a1, b0, acc10, 0, 0, 0);
        acc11 = MFMA16(a1, b1, acc11, 0, 0, 0);
    }
#pragma unroll
    for (int am = 0; am < 2; am++) {
#pragma unroll
        for (int r = 0; r < 4; r++) {
            const int cm = m0 + am * 16 + h4 * 4 + r;
#pragma unroll
            for (int bn = 0; bn < 2; bn++) {
                float v = am ? (bn ? acc11[r] : acc10[r]) : (bn ? acc01[r] : acc00[r]);
                out[cm * 256 + n0 + bn * 16 + cl] = v;
            }
        }
    }
}

extern "C" void kernel_launch(void* const* d_in, const int* in_sizes, int n_in,
                              void* d_out, int out_size, void* d_ws, size_t ws_size,
                              hipStream_t stream) {
    const float* query = (const float*)d_in[0];
    const float* key_ = (const float*)d_in[1];
    const float* value = (const float*)d_in[2];
    const float* radial = (const float*)d_in[3];
    const float* Wq = (const float*)d_in[4];
    const float* Wk = (const float*)d_in[5];
    const float* Wv = (const float*)d_in[6];
    const float* Wo = (const float*)d_in[7];

    const size_t MB = 1u << 20;
    uint8_t* base = (uint8_t*)d_ws;
    unsigned short* wq = (unsigned short*)(base + 0 * MB);
    unsigned short* wk = (unsigned short*)(base + 2 * MB);
    unsigned short* wv = (unsigned short*)(base + 4 * MB);
    unsigned short* wa = (unsigned short*)(base + 6 * MB);

    if (ws_size >= (size_t)(15.5 * 1024 * 1024)) {
        unsigned short* bX0 = (unsigned short*)(base + 8 * MB);
        unsigned short* bX1 = (unsigned short*)(base + 10 * MB);
        unsigned short* bX2 = (unsigned short*)(base + 12 * MB);
        unsigned short* bWq = (unsigned short*)(base + 14 * MB);
        unsigned short* bWk = (unsigned short*)(base + 14 * MB + 128 * 1024);
        unsigned short* bWv = (unsigned short*)(base + 14 * MB + 256 * 1024);
        unsigned short* bWo = (unsigned short*)(base + 14 * MB + 384 * 1024);
        precvt_kernel<<<1664, 256, 0, stream>>>(query, key_, value, Wq, Wk, Wv, Wo,
                                                bX0, bX1, bX2, bWq, bWk, bWv, bWo);
        proj_bf16_kernel<<<dim3(256, 3), 256, 0, stream>>>(bX0, bX1, bX2, bWq, bWk, bWv,
                                                           radial, wq, wk, wv);
        attn_kernel<<<512, 512, 0, stream>>>(wq, wk, wv, wa);
        oproj_bf16_kernel<<<512, 256, 0, stream>>>(wa, bWo, (float*)d_out);
    } else {
        proj_f32_kernel<<<dim3(256, 3), 256, 0, stream>>>(query, key_, value, Wq, Wk, Wv,
                                                          radial, wq, wk, wv);
        attn_kernel<<<512, 512, 0, stream>>>(wq, wk, wv, wa);
        oproj_f32_kernel<<<256, 256, 0, stream>>>(wa, Wo, (float*)d_out);
    }
}